// Round 6
// baseline (2578.571 us; speedup 1.0000x reference)
//
#include <hip/hip_runtime.h>
#include <hip/hip_bf16.h>
#include <cstdint>
#include <cstddef>

// GCNClassifier on MI355X.
// R6: XCD feature-sliced aggregation. R5 showed agg FETCH = 415 MB = 8 XCDs x
// 51 MB fp8 footprint: every XCD pulled the whole gather set through its
// private L2. Now grid=(8, N/4); blockIdx.x = 64B feature slice -> with
// round-robin block->XCD dispatch each XCD only ever touches its own 6.4 MB
// slice (L2-resident). A wave covers 8 edges x 64B per gather instruction
// (8 lane-groups x 8 lanes x 8B); shfl_xor(8/16/32) butterfly combines edge
// partials. VALU instruction count per edge unchanged vs R5.
// Carried: fp8 e4m3 agg payload, L4 reordered to (agg h3)@W4, bias+leaky in
// GEMM4 epilogue, fp32 accumulation, nt hout stores.

typedef unsigned short u16;
typedef unsigned char u8;
typedef unsigned int u32;
typedef __bf16 bf16x8 __attribute__((ext_vector_type(8)));
typedef u16 u16x8 __attribute__((ext_vector_type(8)));
typedef u32 u32x2 __attribute__((ext_vector_type(2)));
typedef float f32x2 __attribute__((ext_vector_type(2)));
typedef float f32x4 __attribute__((ext_vector_type(4)));

__device__ __forceinline__ u16 f2bf(float f) {
  u32 u = __builtin_bit_cast(u32, f);
  u += 0x7fffu + ((u >> 16) & 1u);   // round-to-nearest-even
  return (u16)(u >> 16);
}
__device__ __forceinline__ float bf2f(u16 h) {
  return __builtin_bit_cast(float, (u32)h << 16);
}
__device__ __forceinline__ void g2lds16(const void* g, void* l) {
  __builtin_amdgcn_global_load_lds((__attribute__((address_space(1))) void*)g,
                                   (__attribute__((address_space(3))) void*)l, 16, 0, 0);
}

// ---------------------------------------------------------------- init / CSR
__global__ __launch_bounds__(256) void init_kernel(int* __restrict__ deg,
                                                   int* __restrict__ cursor,
                                                   float* __restrict__ pool, int N) {
  int i = blockIdx.x * 256 + threadIdx.x;
  if (i < N) { deg[i] = 0; cursor[i] = 0; }
  if (i < 256) pool[i] = 0.f;
}

// Detect int64 vs int32 storage of edge_index (int64 high words are 0 since
// node ids < 1e5; int32 values random in [0,1e5) -> all-zero impossible).
__global__ void detect_kernel(const int* __restrict__ ei, int* __restrict__ flag) {
  __shared__ int nz;
  if (threadIdx.x == 0) nz = 0;
  __syncthreads();
  if (ei[2 * threadIdx.x + 1] != 0) atomicAdd(&nz, 1);
  __syncthreads();
  if (threadIdx.x == 0) *flag = (nz == 0) ? 1 : 0;
}

__device__ __forceinline__ int ld_src(const int* ei, int E, int e, int f64) {
  return f64 ? (int)((const long long*)ei)[e] : ei[e];
}
__device__ __forceinline__ int ld_dst(const int* ei, int E, int e, int f64) {
  return f64 ? (int)((const long long*)ei)[(long long)E + e] : ei[E + e];
}

__global__ __launch_bounds__(256) void degree_kernel(const int* __restrict__ ei,
                                                     const int* __restrict__ flag,
                                                     int* __restrict__ deg, int E) {
  int e = blockIdx.x * 256 + threadIdx.x;
  if (e >= E) return;
  int f = *flag;
  atomicAdd(&deg[ld_dst(ei, E, e, f)], 1);
}

__global__ __launch_bounds__(256) void dis_kernel(const int* __restrict__ deg,
                                                  float* __restrict__ dis, int N) {
  int i = blockIdx.x * 256 + threadIdx.x;
  if (i < N) dis[i] = rsqrtf((float)deg[i] + 1.0f);
}

__global__ __launch_bounds__(1024) void scan1_kernel(const int* __restrict__ deg,
                                                     int* __restrict__ rs,
                                                     int* __restrict__ bsum, int N) {
  __shared__ int s[1024];
  int tid = threadIdx.x;
  int i = blockIdx.x * 1024 + tid;
  int v = (i < N) ? deg[i] : 0;
  s[tid] = v;
  __syncthreads();
  for (int off = 1; off < 1024; off <<= 1) {
    int t = (tid >= off) ? s[tid - off] : 0;
    __syncthreads();
    s[tid] += t;
    __syncthreads();
  }
  if (i < N) rs[i] = s[tid] - v;        // exclusive
  if (tid == 1023) bsum[blockIdx.x] = s[1023];
}

__global__ void scan2_kernel(const int* __restrict__ bsum, int* __restrict__ boff, int nb) {
  if (threadIdx.x == 0) {
    int run = 0;
    for (int b = 0; b < nb; ++b) { boff[b] = run; run += bsum[b]; }
  }
}

__global__ __launch_bounds__(256) void scan3_kernel(int* __restrict__ rs,
                                                    const int* __restrict__ boff, int N) {
  int i = blockIdx.x * 256 + threadIdx.x;
  if (i < N) rs[i] += boff[i >> 10];
}

__global__ __launch_bounds__(256) void fill_kernel(const int* __restrict__ ei,
                                                   const int* __restrict__ flag,
                                                   const int* __restrict__ rs,
                                                   int* __restrict__ cursor,
                                                   int* __restrict__ colv, int E) {
  int e = blockIdx.x * 256 + threadIdx.x;
  if (e >= E) return;
  int f = *flag;
  int s = ld_src(ei, E, e, f);
  int d = ld_dst(ei, E, e, f);
  int p = atomicAdd(&cursor[d], 1);
  colv[rs[d] + p] = s;
}

// ---------------------------------------------------------------- converts
__global__ __launch_bounds__(256) void convx_kernel(const float* __restrict__ x,
                                                    u16* __restrict__ xb, size_t n) {
  size_t i = ((size_t)blockIdx.x * 256 + threadIdx.x) * 4;
  if (i >= n) return;
  float4 v = *reinterpret_cast<const float4*>(x + i);
  typedef u16 u16x4 __attribute__((ext_vector_type(4)));
  u16x4 o;
  o[0] = f2bf(v.x); o[1] = f2bf(v.y); o[2] = f2bf(v.z); o[3] = f2bf(v.w);
  *reinterpret_cast<u16x4*>(xb + i) = o;
}

// W[k][n] fp32 -> Wt[n][k] bf16 (K fixed 512)
__global__ __launch_bounds__(256) void convw_kernel(const float* __restrict__ W,
                                                    u16* __restrict__ Wt, int Nout) {
  int id = blockIdx.x * 256 + threadIdx.x;
  if (id >= 512 * Nout) return;
  int k = id / Nout, n = id - k * Nout;
  Wt[n * 512 + k] = f2bf(W[id]);
}

// ---------------------------------------------------------------- GEMM
// C[M][Nout] = A[M][512] @ W, with Wt[n][k]. 128x128 tile, BK=32, 4 waves 2x2,
// each wave 4x4 tiles of mfma_f32_16x16x32_bf16.
// OUT8: store C as fp8 e4m3 bytes. BACT: add bias + leaky, store bf16.
template <bool OUT8, bool BACT>
__global__ __launch_bounds__(256, 2)
void gemm_kernel(const u16* __restrict__ A, const u16* __restrict__ Bt,
                 void* __restrict__ Cout, const float* __restrict__ bias,
                 int M, int Nout) {
  __shared__ u16 sA[128 * 32];  // [m][k]
  __shared__ u16 sB[128 * 32];  // [n][k]
  const int tid = threadIdx.x;
  const int wave = tid >> 6, lane = tid & 63;
  const int m0 = blockIdx.x * 128;
  const int n0 = blockIdx.y * 128;
  const int wm = (wave >> 1) * 64, wn = (wave & 1) * 64;
  const int lrow = lane >> 2, lchunk = lane & 3;
  const int fr = lane & 15, fq = (lane >> 4) * 8;

  f32x4 acc[4][4];
#pragma unroll
  for (int i = 0; i < 4; ++i)
#pragma unroll
    for (int j = 0; j < 4; ++j) acc[i][j] = (f32x4){0.f, 0.f, 0.f, 0.f};

  for (int k0 = 0; k0 < 512; k0 += 32) {
#pragma unroll
    for (int pss = 0; pss < 2; ++pss) {
      int rbase = pss * 64 + wave * 16;
      int arow = m0 + rbase + lrow;
      arow = arow < M ? arow : M - 1;           // clamp (extra rows never stored)
      g2lds16(A + (size_t)arow * 512 + k0 + lchunk * 8, &sA[rbase * 32]);
      int brow = n0 + rbase + lrow;
      g2lds16(Bt + (size_t)brow * 512 + k0 + lchunk * 8, &sB[rbase * 32]);
    }
    __builtin_amdgcn_s_waitcnt(0);
    __syncthreads();

    bf16x8 af[4], bfr[4];
#pragma unroll
    for (int t = 0; t < 4; ++t) {
      af[t]  = *reinterpret_cast<const bf16x8*>(&sA[(wm + t * 16 + fr) * 32 + fq]);
      bfr[t] = *reinterpret_cast<const bf16x8*>(&sB[(wn + t * 16 + fr) * 32 + fq]);
    }
#pragma unroll
    for (int i = 0; i < 4; ++i)
#pragma unroll
      for (int j = 0; j < 4; ++j)
        acc[i][j] = __builtin_amdgcn_mfma_f32_16x16x32_bf16(af[i], bfr[j], acc[i][j], 0, 0, 0);
    __syncthreads();
  }

  // C/D layout: col = lane&15, row = (lane>>4)*4 + reg  (m89/m91 verified)
  const int crow0 = m0 + wm + ((lane >> 4) << 2);
  const int ccol0 = n0 + wn + (lane & 15);
#pragma unroll
  for (int j = 0; j < 4; ++j) {
    const int col = ccol0 + j * 16;
    float bj = BACT ? bias[col] : 0.f;
#pragma unroll
    for (int i = 0; i < 4; ++i)
#pragma unroll
      for (int r = 0; r < 4; ++r) {
        int row = crow0 + i * 16 + r;
        if (row < M) {
          float v = acc[i][j][r];
          if (BACT) { v += bj; v = v >= 0.f ? v : 0.01f * v; }
          if (OUT8) {
            int e = __builtin_amdgcn_cvt_pk_fp8_f32(v, v, 0, false);
            ((u8*)Cout)[(size_t)row * Nout + col] = (u8)e;
          } else {
            ((u16*)Cout)[(size_t)row * Nout + col] = f2bf(v);
          }
        }
      }
  }
}

// ---------------------------------------------------------------- aggregate
// XCD feature-sliced pull-aggregation over fp8 512B rows.
// grid = (8, ceil(N/4)); blockIdx.x = 64B feature slice (-> one XCD via
// round-robin dispatch), 4 waves/block = 4 nodes. Within a wave: lane = g*8+f,
// edge group g handles edge base+g, feature sub f (8 fp8 features, 8B load).
// One gather instruction covers 8 edges x 64B. Edge-group partials combined
// with shfl_xor(8/16/32). Self loop = virtual edge at index d (weight dd^2);
// groups past the list use s=node, w=0 (redundant loads hit L1).
// ACT: bias+leaky. OUT8: fp8 out (512B rows) else bf16 out (1024B rows).
template <bool ACT, bool OUT8>
__global__ __launch_bounds__(256)
void agg_kernel(const u8* __restrict__ xw, const int* __restrict__ colv,
                const int* __restrict__ rs, const int* __restrict__ deg,
                const float* __restrict__ dis, const float* __restrict__ bias,
                void* __restrict__ hout, int N) {
  const int slice = blockIdx.x;            // 0..7, 64B of the 512B row
  const int wave = threadIdx.x >> 6;
  const int lane = threadIdx.x & 63;
  const int node = blockIdx.y * 4 + wave;
  if (node >= N) return;
  const int g = lane >> 3;                 // edge group 0..7
  const int f = lane & 7;                  // feature sub-block 0..7
  const int start = rs[node];
  const int d = deg[node];
  const float dd = dis[node];
  const size_t fbyte = (size_t)slice * 64 + f * 8;  // byte offset in fp8 row

  f32x2 acc[4];
#pragma unroll
  for (int i = 0; i < 4; ++i) acc[i] = (f32x2){0.f, 0.f};

  const int total = d + 1;                 // edges + self loop
  for (int base = 0; base < total; base += 8) {
    int t = base + g;
    int s = node;
    float w = 0.f;
    if (t < d)       { s = colv[start + t]; w = dd * dis[s]; }
    else if (t == d) { w = dd * dd; }      // self loop
    u32x2 v = *reinterpret_cast<const u32x2*>(xw + (size_t)s * 512 + fbyte);
    f32x2 p0 = __builtin_amdgcn_cvt_pk_f32_fp8((int)v.x, false);
    f32x2 p1 = __builtin_amdgcn_cvt_pk_f32_fp8((int)v.x, true);
    f32x2 p2 = __builtin_amdgcn_cvt_pk_f32_fp8((int)v.y, false);
    f32x2 p3 = __builtin_amdgcn_cvt_pk_f32_fp8((int)v.y, true);
    f32x2 wv = (f32x2){w, w};
    acc[0] += wv * p0;
    acc[1] += wv * p1;
    acc[2] += wv * p2;
    acc[3] += wv * p3;
  }

  // reduce across the 8 edge groups (lane bits 3,4,5)
#pragma unroll
  for (int m = 8; m <= 32; m <<= 1) {
#pragma unroll
    for (int i = 0; i < 4; ++i) {
      acc[i].x += __shfl_xor(acc[i].x, m);
      acc[i].y += __shfl_xor(acc[i].y, m);
    }
  }

  if (g == 0) {                            // lanes 0..7 hold the slice result
    float h[8];
#pragma unroll
    for (int i = 0; i < 8; ++i) {
      float v = (i & 1) ? acc[i >> 1].y : acc[i >> 1].x;
      if (ACT) {
        v += bias[slice * 64 + f * 8 + i];
        v = v >= 0.f ? v : 0.01f * v;
      }
      h[i] = v;
    }
    if (OUT8) {
      int lo = __builtin_amdgcn_cvt_pk_fp8_f32(h[0], h[1], 0, false);
      lo = __builtin_amdgcn_cvt_pk_fp8_f32(h[2], h[3], lo, true);
      int hi = __builtin_amdgcn_cvt_pk_fp8_f32(h[4], h[5], 0, false);
      hi = __builtin_amdgcn_cvt_pk_fp8_f32(h[6], h[7], hi, true);
      u32x2 o; o.x = (u32)lo; o.y = (u32)hi;
      __builtin_nontemporal_store(o,
          reinterpret_cast<u32x2*>((u8*)hout + (size_t)node * 512 + fbyte));
    } else {
      u16x8 o;
#pragma unroll
      for (int i = 0; i < 8; ++i) o[i] = f2bf(h[i]);
      __builtin_nontemporal_store(o,
          reinterpret_cast<u16x8*>((u16*)hout + (size_t)node * 512 + slice * 64 + f * 8));
    }
  }
}

// ---------------------------------------------------------------- pool + FC
// 256 blocks x 256 threads; thread (rg=tid>>5, fg=tid&31) accumulates 8
// features (16B loads); LDS reduce across 8 row-groups; 256 atomics/block.
__global__ __launch_bounds__(256) void pool_kernel(const u16* __restrict__ h,
                                                   float* __restrict__ pool, int N) {
  __shared__ float lds[8 * 256];
  const int tid = threadIdx.x;
  const int fg = tid & 31;
  const int rg = tid >> 5;
  float acc[8];
#pragma unroll
  for (int i = 0; i < 8; ++i) acc[i] = 0.f;
  for (int r = blockIdx.x * 8 + rg; r < N; r += gridDim.x * 8) {
    u16x8 v = *reinterpret_cast<const u16x8*>(h + (size_t)r * 256 + fg * 8);
#pragma unroll
    for (int i = 0; i < 8; ++i) acc[i] += bf2f(v[i]);
  }
#pragma unroll
  for (int i = 0; i < 8; ++i) lds[rg * 256 + fg * 8 + i] = acc[i];
  __syncthreads();
  float s = 0.f;
#pragma unroll
  for (int g = 0; g < 8; ++g) s += lds[g * 256 + tid];
  atomicAdd(&pool[tid], s);
}

__global__ void fc_kernel(const float* __restrict__ pool, const float* __restrict__ fcW1,
                          const float* __restrict__ fcb1, const float* __restrict__ fcW2,
                          const float* __restrict__ fcb2, float* __restrict__ out,
                          float invN) {
  int j = threadIdx.x;  // 64 threads = 1 wave
  float acc = 0.f;
  for (int f = 0; f < 256; ++f) acc += pool[f] * invN * fcW1[f * 64 + j];
  float h = acc + fcb1[j];
  h = h >= 0.f ? h : 0.01f * h;
  float p = h * fcW2[j];
  for (int o = 32; o; o >>= 1) p += __shfl_down(p, o);
  if (j == 0) out[0] = 1.f / (1.f + expf(-(p + fcb2[0])));
}

// ---------------------------------------------------------------- launch
extern "C" void kernel_launch(void* const* d_in, const int* in_sizes, int n_in,
                              void* d_out, int out_size, void* d_ws, size_t ws_size,
                              hipStream_t stream) {
  const float* x    = (const float*)d_in[0];
  const int*   ei   = (const int*)d_in[1];
  const float* W1   = (const float*)d_in[2];
  const float* b1   = (const float*)d_in[3];
  const float* W2   = (const float*)d_in[4];
  const float* b2   = (const float*)d_in[5];
  const float* W3   = (const float*)d_in[6];
  const float* b3   = (const float*)d_in[7];
  const float* W4   = (const float*)d_in[8];
  const float* b4   = (const float*)d_in[9];
  const float* fcW1 = (const float*)d_in[10];
  const float* fcb1 = (const float*)d_in[11];
  const float* fcW2 = (const float*)d_in[12];
  const float* fcb2 = (const float*)d_in[13];
  float* out = (float*)d_out;

  const int N = in_sizes[0] / 512;
  const int E = in_sizes[1] / 2;

  char* p = (char*)d_ws;
  auto carve = [&](size_t bytes) {
    char* r = p;
    p += (bytes + 255) & ~(size_t)255;
    return r;
  };
  u16* bufX = (u16*)carve((size_t)N * 512 * 2);  // x; h2; h4(256w)
  u16* bufH = (u16*)carve((size_t)N * 512 * 2);  // h1; g4
  u8*  bufP = (u8*)carve((size_t)N * 512);       // fp8 xw per layer
  u8*  bufQ = (u8*)carve((size_t)N * 512);       // fp8 h3
  u16* Wt1 = (u16*)carve(512 * 512 * 2);
  u16* Wt2 = (u16*)carve(512 * 512 * 2);
  u16* Wt3 = (u16*)carve(512 * 512 * 2);
  u16* Wt4 = (u16*)carve(512 * 256 * 2);
  int* deg    = (int*)carve((size_t)N * 4);
  int* cursor = (int*)carve((size_t)N * 4);
  int* rs     = (int*)carve((size_t)(N + 1) * 4);
  int* colv   = (int*)carve((size_t)E * 4);
  int* bsum   = (int*)carve(1024 * 4);
  int* boff   = (int*)carve(1024 * 4);
  int* flag   = (int*)carve(256);
  float* disv = (float*)carve((size_t)N * 4);
  float* pool = (float*)carve(256 * 4);
  if ((size_t)(p - (char*)d_ws) > ws_size) return;  // need ~320 MB

  const int nb1024 = (N + 1023) / 1024;

  init_kernel<<<(N + 255) / 256, 256, 0, stream>>>(deg, cursor, pool, N);
  detect_kernel<<<1, 256, 0, stream>>>(ei, flag);
  degree_kernel<<<(E + 255) / 256, 256, 0, stream>>>(ei, flag, deg, E);
  dis_kernel<<<(N + 255) / 256, 256, 0, stream>>>(deg, disv, N);
  scan1_kernel<<<nb1024, 1024, 0, stream>>>(deg, rs, bsum, N);
  scan2_kernel<<<1, 64, 0, stream>>>(bsum, boff, nb1024);
  scan3_kernel<<<(N + 255) / 256, 256, 0, stream>>>(rs, boff, N);
  fill_kernel<<<(E + 255) / 256, 256, 0, stream>>>(ei, flag, rs, cursor, colv, E);

  convx_kernel<<<((size_t)N * 512 / 4 + 255) / 256, 256, 0, stream>>>(x, bufX, (size_t)N * 512);
  convw_kernel<<<(512 * 512 + 255) / 256, 256, 0, stream>>>(W1, Wt1, 512);
  convw_kernel<<<(512 * 512 + 255) / 256, 256, 0, stream>>>(W2, Wt2, 512);
  convw_kernel<<<(512 * 512 + 255) / 256, 256, 0, stream>>>(W3, Wt3, 512);
  convw_kernel<<<(512 * 256 + 255) / 256, 256, 0, stream>>>(W4, Wt4, 256);

  const unsigned gm = (unsigned)((N + 127) / 128);
  const unsigned ga = (unsigned)((N + 3) / 4);

  // L1: xw1 = x@W1 (fp8) ; h1 = leaky(agg xw1 + b1) (bf16)
  gemm_kernel<true, false><<<dim3(gm, 4), 256, 0, stream>>>(bufX, Wt1, bufP, nullptr, N, 512);
  agg_kernel<true, false><<<dim3(8, ga), 256, 0, stream>>>(bufP, colv, rs, deg, disv, b1, bufH, N);
  // L2: xw2 = h1@W2 (fp8) ; h2 = leaky(agg xw2 + b2) (bf16)
  gemm_kernel<true, false><<<dim3(gm, 4), 256, 0, stream>>>(bufH, Wt2, bufP, nullptr, N, 512);
  agg_kernel<true, false><<<dim3(8, ga), 256, 0, stream>>>(bufP, colv, rs, deg, disv, b2, bufX, N);
  // L3: xw3 = h2@W3 (fp8) ; h3 = leaky(agg xw3 + b3) (fp8)
  gemm_kernel<true, false><<<dim3(gm, 4), 256, 0, stream>>>(bufX, Wt3, bufP, nullptr, N, 512);
  agg_kernel<true, true><<<dim3(8, ga), 256, 0, stream>>>(bufP, colv, rs, deg, disv, b3, bufQ, N);
  // L4 reordered: g4 = agg h3 (bf16, no act) ; h4 = leaky(g4@W4 + b4) (bf16)
  agg_kernel<false, false><<<dim3(8, ga), 256, 0, stream>>>(bufQ, colv, rs, deg, disv, nullptr, bufH, N);
  gemm_kernel<false, true><<<dim3(gm, 2), 256, 0, stream>>>(bufH, Wt4, bufX, b4, N, 256);

  pool_kernel<<<256, 256, 0, stream>>>(bufX, pool, N);
  fc_kernel<<<1, 64, 0, stream>>>(pool, fcW1, fcb1, fcW2, fcb2, out, 1.0f / (float)N);
}

// Round 7
// 1275.679 us; speedup vs baseline: 2.0213x; 2.0213x over previous
//
#include <hip/hip_runtime.h>
#include <hip/hip_bf16.h>
#include <cstdint>
#include <cstddef>

// GCNClassifier on MI355X.
// R7: agg reverted to R5 form (full-row 512B fp8 gathers, readlane-batched,
// at its L3 random-access floor ~127us). R6's XCD slicing removed (6.4MB
// slice > 4MiB L2 -> thrashed). New: ALL GEMMs use fp8x8 MFMA
// (mfma_f32_16x16x32_fp8_fp8) with fp8 activations+weights end-to-end,
// halving GEMM staging work and fetch traffic; scan2 parallelized.

typedef unsigned short u16;
typedef unsigned char u8;
typedef unsigned int u32;
typedef u16 u16x8 __attribute__((ext_vector_type(8)));
typedef u32 u32x2 __attribute__((ext_vector_type(2)));
typedef float f32x2 __attribute__((ext_vector_type(2)));
typedef float f32x4 __attribute__((ext_vector_type(4)));

__device__ __forceinline__ u16 f2bf(float f) {
  u32 u = __builtin_bit_cast(u32, f);
  u += 0x7fffu + ((u >> 16) & 1u);   // round-to-nearest-even
  return (u16)(u >> 16);
}
__device__ __forceinline__ float bf2f(u16 h) {
  return __builtin_bit_cast(float, (u32)h << 16);
}
__device__ __forceinline__ void g2lds16(const void* g, void* l) {
  __builtin_amdgcn_global_load_lds((__attribute__((address_space(1))) void*)g,
                                   (__attribute__((address_space(3))) void*)l, 16, 0, 0);
}

// ---------------------------------------------------------------- init / CSR
__global__ __launch_bounds__(256) void init_kernel(int* __restrict__ deg,
                                                   int* __restrict__ cursor,
                                                   float* __restrict__ pool, int N) {
  int i = blockIdx.x * 256 + threadIdx.x;
  if (i < N) { deg[i] = 0; cursor[i] = 0; }
  if (i < 256) pool[i] = 0.f;
}

// Detect int64 vs int32 storage of edge_index (int64 high words are 0 since
// node ids < 1e5; int32 values random in [0,1e5) -> all-zero impossible).
__global__ void detect_kernel(const int* __restrict__ ei, int* __restrict__ flag) {
  __shared__ int nz;
  if (threadIdx.x == 0) nz = 0;
  __syncthreads();
  if (ei[2 * threadIdx.x + 1] != 0) atomicAdd(&nz, 1);
  __syncthreads();
  if (threadIdx.x == 0) *flag = (nz == 0) ? 1 : 0;
}

__device__ __forceinline__ int ld_src(const int* ei, int E, int e, int f64) {
  return f64 ? (int)((const long long*)ei)[e] : ei[e];
}
__device__ __forceinline__ int ld_dst(const int* ei, int E, int e, int f64) {
  return f64 ? (int)((const long long*)ei)[(long long)E + e] : ei[E + e];
}

__global__ __launch_bounds__(256) void degree_kernel(const int* __restrict__ ei,
                                                     const int* __restrict__ flag,
                                                     int* __restrict__ deg, int E) {
  int e = blockIdx.x * 256 + threadIdx.x;
  if (e >= E) return;
  int f = *flag;
  atomicAdd(&deg[ld_dst(ei, E, e, f)], 1);
}

__global__ __launch_bounds__(256) void dis_kernel(const int* __restrict__ deg,
                                                  float* __restrict__ dis, int N) {
  int i = blockIdx.x * 256 + threadIdx.x;
  if (i < N) dis[i] = rsqrtf((float)deg[i] + 1.0f);
}

__global__ __launch_bounds__(1024) void scan1_kernel(const int* __restrict__ deg,
                                                     int* __restrict__ rs,
                                                     int* __restrict__ bsum, int N) {
  __shared__ int s[1024];
  int tid = threadIdx.x;
  int i = blockIdx.x * 1024 + tid;
  int v = (i < N) ? deg[i] : 0;
  s[tid] = v;
  __syncthreads();
  for (int off = 1; off < 1024; off <<= 1) {
    int t = (tid >= off) ? s[tid - off] : 0;
    __syncthreads();
    s[tid] += t;
    __syncthreads();
  }
  if (i < N) rs[i] = s[tid] - v;        // exclusive
  if (tid == 1023) bsum[blockIdx.x] = s[1023];
}

// parallel block-offset scan (nb <= 1024)
__global__ __launch_bounds__(1024) void scan2_kernel(const int* __restrict__ bsum,
                                                     int* __restrict__ boff, int nb) {
  __shared__ int s[1024];
  int tid = threadIdx.x;
  int v = (tid < nb) ? bsum[tid] : 0;
  s[tid] = v;
  __syncthreads();
  for (int off = 1; off < 1024; off <<= 1) {
    int t = (tid >= off) ? s[tid - off] : 0;
    __syncthreads();
    s[tid] += t;
    __syncthreads();
  }
  if (tid < nb) boff[tid] = s[tid] - v;  // exclusive
}

__global__ __launch_bounds__(256) void scan3_kernel(int* __restrict__ rs,
                                                    const int* __restrict__ boff, int N) {
  int i = blockIdx.x * 256 + threadIdx.x;
  if (i < N) rs[i] += boff[i >> 10];
}

__global__ __launch_bounds__(256) void fill_kernel(const int* __restrict__ ei,
                                                   const int* __restrict__ flag,
                                                   const int* __restrict__ rs,
                                                   int* __restrict__ cursor,
                                                   int* __restrict__ colv, int E) {
  int e = blockIdx.x * 256 + threadIdx.x;
  if (e >= E) return;
  int f = *flag;
  int s = ld_src(ei, E, e, f);
  int d = ld_dst(ei, E, e, f);
  int p = atomicAdd(&cursor[d], 1);
  colv[rs[d] + p] = s;
}

// ---------------------------------------------------------------- converts
// x fp32 -> fp8 (4 values/thread)
__global__ __launch_bounds__(256) void convx_kernel(const float* __restrict__ x,
                                                    u8* __restrict__ x8, size_t n) {
  size_t i = ((size_t)blockIdx.x * 256 + threadIdx.x) * 4;
  if (i >= n) return;
  float4 v = *reinterpret_cast<const float4*>(x + i);
  int lo = __builtin_amdgcn_cvt_pk_fp8_f32(v.x, v.y, 0, false);
  int r = __builtin_amdgcn_cvt_pk_fp8_f32(v.z, v.w, lo, true);
  *reinterpret_cast<u32*>(x8 + i) = (u32)r;
}

// W[k][n] fp32 -> Wt[n][k] fp8 (K fixed 512)
__global__ __launch_bounds__(256) void convw_kernel(const float* __restrict__ W,
                                                    u8* __restrict__ Wt, int Nout) {
  int id = blockIdx.x * 256 + threadIdx.x;
  if (id >= 512 * Nout) return;
  int k = id / Nout, n = id - k * Nout;
  float v = W[id];
  int e = __builtin_amdgcn_cvt_pk_fp8_f32(v, v, 0, false);
  Wt[n * 512 + k] = (u8)e;
}

// ---------------------------------------------------------------- GEMM (fp8)
// C[M][Nout] = A[M][512] @ W, A and Wt[n][k] in fp8 e4m3. 128x128 tile,
// BK=32 (32B rows in LDS), 4 waves 2x2, each wave 4x4 tiles of
// mfma_f32_16x16x32_fp8_fp8 (8B A/B fragments per lane).
// Staging: 2 global_load_lds_dwordx4 per thread per k-step (A+B).
// OUT8: store fp8. BACT: add bias + leaky, store bf16.
template <bool OUT8, bool BACT>
__global__ __launch_bounds__(256, 2)
void gemm8_kernel(const u8* __restrict__ A, const u8* __restrict__ Bt,
                  void* __restrict__ Cout, const float* __restrict__ bias,
                  int M, int Nout) {
  __shared__ u8 sA[128 * 32];  // [m][k] 32B rows
  __shared__ u8 sB[128 * 32];  // [n][k]
  const int tid = threadIdx.x;
  const int wave = tid >> 6, lane = tid & 63;
  const int m0 = blockIdx.x * 128;
  const int n0 = blockIdx.y * 128;
  const int wm = (wave >> 1) * 64, wn = (wave & 1) * 64;
  const int srow = wave * 32 + (lane >> 1);     // staging row (32 rows/wave)
  const int soff = (lane & 1) * 16;             // 16B chunk within 32B row
  const int fr = lane & 15, fq8 = (lane >> 4) * 8;

  f32x4 acc[4][4];
#pragma unroll
  for (int i = 0; i < 4; ++i)
#pragma unroll
    for (int j = 0; j < 4; ++j) acc[i][j] = (f32x4){0.f, 0.f, 0.f, 0.f};

  for (int k0 = 0; k0 < 512; k0 += 32) {
    {
      int arow = m0 + srow;
      arow = arow < M ? arow : M - 1;           // clamp (extra rows never stored)
      g2lds16(A + (size_t)arow * 512 + k0 + soff, &sA[(wave * 32) * 32]);
      int brow = n0 + srow;
      g2lds16(Bt + (size_t)brow * 512 + k0 + soff, &sB[(wave * 32) * 32]);
    }
    __builtin_amdgcn_s_waitcnt(0);
    __syncthreads();

    long long af[4], bf[4];
#pragma unroll
    for (int t = 0; t < 4; ++t) {
      af[t] = *reinterpret_cast<const long long*>(&sA[(wm + t * 16 + fr) * 32 + fq8]);
      bf[t] = *reinterpret_cast<const long long*>(&sB[(wn + t * 16 + fr) * 32 + fq8]);
    }
#pragma unroll
    for (int i = 0; i < 4; ++i)
#pragma unroll
      for (int j = 0; j < 4; ++j)
        acc[i][j] = __builtin_amdgcn_mfma_f32_16x16x32_fp8_fp8(af[i], bf[j], acc[i][j], 0, 0, 0);
    __syncthreads();
  }

  // C/D layout: col = lane&15, row = (lane>>4)*4 + reg  (dtype-independent)
  const int crow0 = m0 + wm + ((lane >> 4) << 2);
  const int ccol0 = n0 + wn + (lane & 15);
#pragma unroll
  for (int j = 0; j < 4; ++j) {
    const int col = ccol0 + j * 16;
    float bj = BACT ? bias[col] : 0.f;
#pragma unroll
    for (int i = 0; i < 4; ++i)
#pragma unroll
      for (int r = 0; r < 4; ++r) {
        int row = crow0 + i * 16 + r;
        if (row < M) {
          float v = acc[i][j][r];
          if (BACT) { v += bj; v = v >= 0.f ? v : 0.01f * v; }
          if (OUT8) {
            int e = __builtin_amdgcn_cvt_pk_fp8_f32(v, v, 0, false);
            ((u8*)Cout)[(size_t)row * Nout + col] = (u8)e;
          } else {
            ((u16*)Cout)[(size_t)row * Nout + col] = f2bf(v);
          }
        }
      }
  }
}

// ---------------------------------------------------------------- aggregate
// R5 structure: one wave per node, fp8 512B rows (8B/lane). Batched index
// fetch (colv[start+lane]), inner loop broadcasts (s,w) via v_readlane and
// issues 8 independent 512B row gathers per iter. Decode v_cvt_pk_f32_fp8,
// packed f32x2 accumulation, non-temporal fp8 output.
// Self loop = virtual edge at index d. ACT: bias+leaky.
template <bool ACT>
__global__ __launch_bounds__(256)
void agg_kernel(const u8* __restrict__ xw, const int* __restrict__ colv,
                const int* __restrict__ rs, const int* __restrict__ deg,
                const float* __restrict__ dis, const float* __restrict__ bias,
                u8* __restrict__ hout, int N) {
  const int wave = threadIdx.x >> 6;
  const int lane = threadIdx.x & 63;
  const int node = blockIdx.x * 4 + wave;
  if (node >= N) return;
  const int start = rs[node];
  const int d = deg[node];
  const float dd = dis[node];
  const int fo = lane * 8;   // byte offset within 512B row

  f32x2 acc[4];
#pragma unroll
  for (int i = 0; i < 4; ++i) acc[i] = (f32x2){0.f, 0.f};

  const int total = d + 1;                      // edges + self loop
  for (int base = 0; base < total; base += 64) {
    int t = base + lane;
    int s = node;
    float w = 0.f;
    if (t < d)       { s = colv[start + t]; w = dd * dis[s]; }
    else if (t == d) { w = dd * dd; }           // self loop
    int cnt = total - base;
    if (cnt > 64) cnt = 64;
    int cnt8 = (cnt + 7) & ~7;
    int wi = __builtin_bit_cast(int, w);
    for (int j = 0; j < cnt8; j += 8) {
      u32x2 v[8];
      float ws[8];
#pragma unroll
      for (int k = 0; k < 8; ++k) {
        int sk = __builtin_amdgcn_readlane(s, j + k);
        ws[k] = __builtin_bit_cast(float, __builtin_amdgcn_readlane(wi, j + k));
        v[k] = *reinterpret_cast<const u32x2*>(xw + (size_t)sk * 512 + fo);
      }
#pragma unroll
      for (int k = 0; k < 8; ++k) {
        f32x2 p0 = __builtin_amdgcn_cvt_pk_f32_fp8((int)v[k].x, false);
        f32x2 p1 = __builtin_amdgcn_cvt_pk_f32_fp8((int)v[k].x, true);
        f32x2 p2 = __builtin_amdgcn_cvt_pk_f32_fp8((int)v[k].y, false);
        f32x2 p3 = __builtin_amdgcn_cvt_pk_f32_fp8((int)v[k].y, true);
        f32x2 wv = (f32x2){ws[k], ws[k]};
        acc[0] += wv * p0;
        acc[1] += wv * p1;
        acc[2] += wv * p2;
        acc[3] += wv * p3;
      }
    }
  }

  float h[8];
#pragma unroll
  for (int i = 0; i < 8; ++i) {
    float v = (i & 1) ? acc[i >> 1].y : acc[i >> 1].x;
    if (ACT) { v += bias[fo + i]; v = v >= 0.f ? v : 0.01f * v; }
    h[i] = v;
  }
  int lo = __builtin_amdgcn_cvt_pk_fp8_f32(h[0], h[1], 0, false);
  lo = __builtin_amdgcn_cvt_pk_fp8_f32(h[2], h[3], lo, true);
  int hi = __builtin_amdgcn_cvt_pk_fp8_f32(h[4], h[5], 0, false);
  hi = __builtin_amdgcn_cvt_pk_fp8_f32(h[6], h[7], hi, true);
  u32x2 o; o.x = (u32)lo; o.y = (u32)hi;
  __builtin_nontemporal_store(o, reinterpret_cast<u32x2*>(hout + (size_t)node * 512 + fo));
}

// ---------------------------------------------------------------- pool + FC
// 256 blocks x 256 threads; thread (rg=tid>>5, fg=tid&31) accumulates 8
// features (16B loads); LDS reduce across 8 row-groups; 256 atomics/block.
__global__ __launch_bounds__(256) void pool_kernel(const u16* __restrict__ h,
                                                   float* __restrict__ pool, int N) {
  __shared__ float lds[8 * 256];
  const int tid = threadIdx.x;
  const int fg = tid & 31;
  const int rg = tid >> 5;
  float acc[8];
#pragma unroll
  for (int i = 0; i < 8; ++i) acc[i] = 0.f;
  for (int r = blockIdx.x * 8 + rg; r < N; r += gridDim.x * 8) {
    u16x8 v = *reinterpret_cast<const u16x8*>(h + (size_t)r * 256 + fg * 8);
#pragma unroll
    for (int i = 0; i < 8; ++i) acc[i] += bf2f(v[i]);
  }
#pragma unroll
  for (int i = 0; i < 8; ++i) lds[rg * 256 + fg * 8 + i] = acc[i];
  __syncthreads();
  float s = 0.f;
#pragma unroll
  for (int g = 0; g < 8; ++g) s += lds[g * 256 + tid];
  atomicAdd(&pool[tid], s);
}

__global__ void fc_kernel(const float* __restrict__ pool, const float* __restrict__ fcW1,
                          const float* __restrict__ fcb1, const float* __restrict__ fcW2,
                          const float* __restrict__ fcb2, float* __restrict__ out,
                          float invN) {
  int j = threadIdx.x;  // 64 threads = 1 wave
  float acc = 0.f;
  for (int f = 0; f < 256; ++f) acc += pool[f] * invN * fcW1[f * 64 + j];
  float h = acc + fcb1[j];
  h = h >= 0.f ? h : 0.01f * h;
  float p = h * fcW2[j];
  for (int o = 32; o; o >>= 1) p += __shfl_down(p, o);
  if (j == 0) out[0] = 1.f / (1.f + expf(-(p + fcb2[0])));
}

// ---------------------------------------------------------------- launch
extern "C" void kernel_launch(void* const* d_in, const int* in_sizes, int n_in,
                              void* d_out, int out_size, void* d_ws, size_t ws_size,
                              hipStream_t stream) {
  const float* x    = (const float*)d_in[0];
  const int*   ei   = (const int*)d_in[1];
  const float* W1   = (const float*)d_in[2];
  const float* b1   = (const float*)d_in[3];
  const float* W2   = (const float*)d_in[4];
  const float* b2   = (const float*)d_in[5];
  const float* W3   = (const float*)d_in[6];
  const float* b3   = (const float*)d_in[7];
  const float* W4   = (const float*)d_in[8];
  const float* b4   = (const float*)d_in[9];
  const float* fcW1 = (const float*)d_in[10];
  const float* fcb1 = (const float*)d_in[11];
  const float* fcW2 = (const float*)d_in[12];
  const float* fcb2 = (const float*)d_in[13];
  float* out = (float*)d_out;

  const int N = in_sizes[0] / 512;
  const int E = in_sizes[1] / 2;

  char* p = (char*)d_ws;
  auto carve = [&](size_t bytes) {
    char* r = p;
    p += (bytes + 255) & ~(size_t)255;
    return r;
  };
  u8*  bufX = (u8*)carve((size_t)N * 512);       // fp8: x8; h2; g4
  u8*  bufP = (u8*)carve((size_t)N * 512);       // fp8: xw per layer
  u8*  bufQ = (u8*)carve((size_t)N * 512);       // fp8: h1; h3
  u16* bufH4 = (u16*)carve((size_t)N * 256 * 2); // bf16 h4 for pool
  u8* Wt1 = (u8*)carve(512 * 512);
  u8* Wt2 = (u8*)carve(512 * 512);
  u8* Wt3 = (u8*)carve(512 * 512);
  u8* Wt4 = (u8*)carve(512 * 256);
  int* deg    = (int*)carve((size_t)N * 4);
  int* cursor = (int*)carve((size_t)N * 4);
  int* rs     = (int*)carve((size_t)(N + 1) * 4);
  int* colv   = (int*)carve((size_t)E * 4);
  int* bsum   = (int*)carve(1024 * 4);
  int* boff   = (int*)carve(1024 * 4);
  int* flag   = (int*)carve(256);
  float* disv = (float*)carve((size_t)N * 4);
  float* pool = (float*)carve(256 * 4);
  if ((size_t)(p - (char*)d_ws) > ws_size) return;  // need ~230 MB

  const int nb1024 = (N + 1023) / 1024;

  init_kernel<<<(N + 255) / 256, 256, 0, stream>>>(deg, cursor, pool, N);
  detect_kernel<<<1, 256, 0, stream>>>(ei, flag);
  degree_kernel<<<(E + 255) / 256, 256, 0, stream>>>(ei, flag, deg, E);
  dis_kernel<<<(N + 255) / 256, 256, 0, stream>>>(deg, disv, N);
  scan1_kernel<<<nb1024, 1024, 0, stream>>>(deg, rs, bsum, N);
  scan2_kernel<<<1, 1024, 0, stream>>>(bsum, boff, nb1024);
  scan3_kernel<<<(N + 255) / 256, 256, 0, stream>>>(rs, boff, N);
  fill_kernel<<<(E + 255) / 256, 256, 0, stream>>>(ei, flag, rs, cursor, colv, E);

  convx_kernel<<<((size_t)N * 512 / 4 + 255) / 256, 256, 0, stream>>>(x, bufX, (size_t)N * 512);
  convw_kernel<<<(512 * 512 + 255) / 256, 256, 0, stream>>>(W1, Wt1, 512);
  convw_kernel<<<(512 * 512 + 255) / 256, 256, 0, stream>>>(W2, Wt2, 512);
  convw_kernel<<<(512 * 512 + 255) / 256, 256, 0, stream>>>(W3, Wt3, 512);
  convw_kernel<<<(512 * 256 + 255) / 256, 256, 0, stream>>>(W4, Wt4, 256);

  const unsigned gm = (unsigned)((N + 127) / 128);
  const unsigned ga = (unsigned)((N + 3) / 4);

  // L1: xw1 = x8@W1 (fp8) ; h1 = leaky(agg xw1 + b1) (fp8)
  gemm8_kernel<true, false><<<dim3(gm, 4), 256, 0, stream>>>(bufX, Wt1, bufP, nullptr, N, 512);
  agg_kernel<true><<<ga, 256, 0, stream>>>(bufP, colv, rs, deg, disv, b1, bufQ, N);
  // L2: xw2 = h1@W2 (fp8) ; h2 = leaky(agg xw2 + b2) (fp8)
  gemm8_kernel<true, false><<<dim3(gm, 4), 256, 0, stream>>>(bufQ, Wt2, bufP, nullptr, N, 512);
  agg_kernel<true><<<ga, 256, 0, stream>>>(bufP, colv, rs, deg, disv, b2, bufX, N);
  // L3: xw3 = h2@W3 (fp8) ; h3 = leaky(agg xw3 + b3) (fp8)
  gemm8_kernel<true, false><<<dim3(gm, 4), 256, 0, stream>>>(bufX, Wt3, bufP, nullptr, N, 512);
  agg_kernel<true><<<ga, 256, 0, stream>>>(bufP, colv, rs, deg, disv, b3, bufQ, N);
  // L4 reordered: g4 = agg h3 (fp8, no act) ; h4 = leaky(g4@W4 + b4) (bf16)
  agg_kernel<false><<<ga, 256, 0, stream>>>(bufQ, colv, rs, deg, disv, nullptr, bufX, N);
  gemm8_kernel<false, true><<<dim3(gm, 2), 256, 0, stream>>>(bufX, Wt4, bufH4, b4, N, 256);

  pool_kernel<<<256, 256, 0, stream>>>(bufH4, pool, N);
  fc_kernel<<<1, 64, 0, stream>>>(pool, fcW1, fcb1, fcW2, fcb2, out, 1.0f / (float)N);
}